// Round 2
// baseline (149.453 us; speedup 1.0000x reference)
//
#include <hip/hip_runtime.h>
#include <math.h>

#ifndef M_PI
#define M_PI 3.14159265358979323846
#endif

#define BATCHES 256
#define S_LEN   131072

__device__ __forceinline__ void compute_coeffs(float level_in, float b0[3], float na1[3], float na2[3]) {
    const float FD[3] = {270.0f, 800.0f, 2300.0f};
    const float FN[3] = {500.0f, 1500.0f, 2500.0f};
    const float FB[3] = {730.0f, 2100.0f, 3000.0f};
    float level = fminf(fmaxf(level_in, 0.0f), 1.0f);
    float t_low  = fminf(fmaxf(level * 2.0f, 0.0f), 1.0f);
    float t_high = fminf(fmaxf((level - 0.5f) * 2.0f, 0.0f), 1.0f);
    bool hi = (level >= 0.5f);
    const float W0 = (float)(2.0 * M_PI / 16000.0);
    #pragma unroll
    for (int k = 0; k < 3; ++k) {
        float f, q;
        if (hi) { f = (1.0f - t_high) * FN[k] + t_high * FB[k];
                  q = (1.0f - t_high) * 8.0f  + t_high * 12.0f; }
        else    { f = (1.0f - t_low) * FD[k] + t_low * FN[k];
                  q = (1.0f - t_low) * 5.0f  + t_low * 8.0f; }
        float omega = W0 * f;
        float sn = sinf(omega), cs = cosf(omega);
        float alpha = sn / (2.0f * fmaxf(q, 0.5f));
        float a0 = 1.0f + alpha;
        b0[k]  = alpha / a0;             // b2 == -b0 exactly
        na1[k] = (2.0f * cs) / a0;       // -a1
        na2[k] = -((1.0f - alpha) / a0); // -a2
    }
}

// One biquad step, 3 bands. Critical chain per band: 1 FMA (na1*y1 + e),
// e depends only on y2 (two steps back) so it's off the critical path.
#define STEP3(XT, XTM2, SUMV)                                                    \
    {                                                                            \
        float d = (XT) - (XTM2);                                                 \
        float e0 = fmaf(b0[0], d, na2[0] * y2[0]);                               \
        float e1 = fmaf(b0[1], d, na2[1] * y2[1]);                               \
        float e2 = fmaf(b0[2], d, na2[2] * y2[2]);                               \
        float yy0 = fmaf(na1[0], y1[0], e0);                                     \
        float yy1 = fmaf(na1[1], y1[1], e1);                                     \
        float yy2 = fmaf(na1[2], y1[2], e2);                                     \
        y2[0] = y1[0]; y1[0] = yy0;                                              \
        y2[1] = y1[1]; y1[1] = yy1;                                              \
        y2[2] = y1[2]; y1[2] = yy2;                                              \
        SUMV = (yy0 + yy1 + yy2);                                                \
    }

// ---------------- K1: zero-state response per chunk ----------------
template<int CHUNK>
__global__ __launch_bounds__(256)
void k1_zerostate(const float* __restrict__ x, const float* __restrict__ level_arr,
                  float* __restrict__ ws)
{
    constexpr int CPR = S_LEN / CHUNK;   // chunks per row
    constexpr int NV  = CHUNK / 4;       // float4s per chunk
    const int g   = blockIdx.x * 256 + threadIdx.x;
    const int row = g / CPR;
    const int c   = g & (CPR - 1);

    float b0[3], na1[3], na2[3];
    compute_coeffs(level_arr[row], b0, na1, na2);

    const float* xc = x + (size_t)row * S_LEN + (size_t)c * CHUNK;
    float xm1 = 0.f, xm2 = 0.f;
    if (c > 0) { float2 t = *(const float2*)(xc - 2); xm2 = t.x; xm1 = t.y; }

    float y1[3] = {0.f, 0.f, 0.f}, y2[3] = {0.f, 0.f, 0.f};
    const float4* xv = (const float4*)xc;
    float4 buf[4];
    #pragma unroll
    for (int j = 0; j < 4; ++j) buf[j] = xv[j];
    float dummy;
    #pragma unroll
    for (int i = 0; i < NV; ++i) {
        float4 q = buf[i & 3];
        if (i + 4 < NV) buf[i & 3] = xv[i + 4];
        STEP3(q.x, xm2, dummy)
        STEP3(q.y, xm1, dummy)
        STEP3(q.z, q.x, dummy)
        STEP3(q.w, q.y, dummy)
        xm2 = q.z; xm1 = q.w;
    }
    (void)dummy;

    // transposed state layout ws[row][elem][chunk] -> coalesced 256B stores
    float* wrow = ws + (size_t)row * 6 * CPR;
    wrow[0 * CPR + c] = y1[0]; wrow[1 * CPR + c] = y2[0];
    wrow[2 * CPR + c] = y1[1]; wrow[3 * CPR + c] = y2[1];
    wrow[4 * CPR + c] = y1[2]; wrow[5 * CPR + c] = y2[2];
}

// ---------------- K2: per-row affine scan over chunk states ----------------
template<int CHUNK>
__global__ __launch_bounds__(192)
void k2_scan(const float* __restrict__ level_arr, float* __restrict__ ws)
{
    constexpr int CPR  = S_LEN / CHUNK;
    constexpr int FOLD = CPR / 64;           // chunks folded per lane
    constexpr int LSTR = CPR + CPR / 32;     // padded LDS stride (2-way max aliasing)
    __shared__ float st[6 * LSTR];

    const int row  = blockIdx.x;
    const int wave = threadIdx.x >> 6;       // 0..2 = band
    const int lane = threadIdx.x & 63;

    float b0[3], na1[3], na2[3];
    compute_coeffs(level_arr[row], b0, na1, na2);
    const float A1 = (wave == 0) ? na1[0] : ((wave == 1) ? na1[1] : na1[2]);
    const float A2 = (wave == 0) ? na2[0] : ((wave == 1) ? na2[1] : na2[2]);

    float* wrow = ws + (size_t)row * 6 * CPR;

    // stage in (coalesced global reads, swizzled LDS writes)
    #pragma unroll
    for (int e = 2 * wave; e <= 2 * wave + 1; ++e)
        for (int i = lane; i < CPR; i += 64)
            st[e * LSTR + i + (i >> 5)] = wrow[e * CPR + i];
    __syncthreads();

    // homogeneous solution over one chunk -> H = [[h1,A2*h2],[h2,A2*h3]]
    float hm1 = 1.f, hm2 = 0.f, hm3 = 0.f;
    for (int i = 0; i < CHUNK; ++i) {
        float h = fmaf(A1, hm1, A2 * hm2);
        hm3 = hm2; hm2 = hm1; hm1 = h;
    }
    const float H00 = hm1, H01 = A2 * hm2;
    const float H10 = hm2, H11 = A2 * hm3;

    float* z1p = st + (2 * wave) * LSTR;
    float* z2p = st + (2 * wave + 1) * LSTR;

    // fold this lane's FOLD chunks
    float s1 = 0.f, s2 = 0.f;
    #pragma unroll
    for (int j = 0; j < FOLD; ++j) {
        int cc = lane * FOLD + j, ca = cc + (cc >> 5);
        float z1 = z1p[ca], z2 = z2p[ca];
        float n1 = z1 + H00 * s1 + H01 * s2;
        float n2 = z2 + H10 * s1 + H11 * s2;
        s1 = n1; s2 = n2;
    }
    // A = H^FOLD via squarings
    float P00 = H00, P01 = H01, P10 = H10, P11 = H11;
    #pragma unroll
    for (int t = 0; (1 << t) < FOLD; ++t) {
        float Q00 = P00 * P00 + P01 * P10;
        float Q01 = P00 * P01 + P01 * P11;
        float Q10 = P10 * P00 + P11 * P10;
        float Q11 = P10 * P01 + P11 * P11;
        P00 = Q00; P01 = Q01; P10 = Q10; P11 = Q11;
    }
    // Kogge-Stone inclusive scan of affine maps
    float A00 = P00, A01 = P01, A10 = P10, A11 = P11, bb1 = s1, bb2 = s2;
    for (int d = 1; d < 64; d <<= 1) {
        float iA00 = __shfl_up(A00, d), iA01 = __shfl_up(A01, d);
        float iA10 = __shfl_up(A10, d), iA11 = __shfl_up(A11, d);
        float ib1  = __shfl_up(bb1, d), ib2  = __shfl_up(bb2, d);
        if (lane >= d) {
            float nb1 = A00 * ib1 + A01 * ib2 + bb1;
            float nb2 = A10 * ib1 + A11 * ib2 + bb2;
            float n00 = A00 * iA00 + A01 * iA10;
            float n01 = A00 * iA01 + A01 * iA11;
            float n10 = A10 * iA00 + A11 * iA10;
            float n11 = A10 * iA01 + A11 * iA11;
            A00 = n00; A01 = n01; A10 = n10; A11 = n11;
            bb1 = nb1; bb2 = nb2;
        }
    }
    float e1 = __shfl_up(bb1, 1), e2 = __shfl_up(bb2, 1);
    if (lane == 0) { e1 = 0.f; e2 = 0.f; }

    // replay: overwrite LDS with corrected chunk-entry states
    s1 = e1; s2 = e2;
    #pragma unroll
    for (int j = 0; j < FOLD; ++j) {
        int cc = lane * FOLD + j, ca = cc + (cc >> 5);
        float z1 = z1p[ca], z2 = z2p[ca];
        z1p[ca] = s1; z2p[ca] = s2;
        float n1 = z1 + H00 * s1 + H01 * s2;
        float n2 = z2 + H10 * s1 + H11 * s2;
        s1 = n1; s2 = n2;
    }
    __syncthreads();

    // stage out (coalesced)
    #pragma unroll
    for (int e = 2 * wave; e <= 2 * wave + 1; ++e)
        for (int i = lane; i < CPR; i += 64)
            wrow[e * CPR + i] = st[e * LSTR + i + (i >> 5)];
}

// ---------------- K3: exact recurrence with corrected entry state ----------------
template<int CHUNK>
__global__ __launch_bounds__(256)
void k3_apply(const float* __restrict__ x, const float* __restrict__ level_arr,
              const float* __restrict__ ws, float* __restrict__ out)
{
    constexpr int CPR = S_LEN / CHUNK;
    constexpr int NV  = CHUNK / 4;
    const int g   = blockIdx.x * 256 + threadIdx.x;
    const int row = g / CPR;
    const int c   = g & (CPR - 1);

    float b0[3], na1[3], na2[3];
    compute_coeffs(level_arr[row], b0, na1, na2);

    const float* wrow = ws + (size_t)row * 6 * CPR;
    float y1[3], y2[3];
    y1[0] = wrow[0 * CPR + c]; y2[0] = wrow[1 * CPR + c];
    y1[1] = wrow[2 * CPR + c]; y2[1] = wrow[3 * CPR + c];
    y1[2] = wrow[4 * CPR + c]; y2[2] = wrow[5 * CPR + c];

    const float* xc = x + (size_t)row * S_LEN + (size_t)c * CHUNK;
    float xm1 = 0.f, xm2 = 0.f;
    if (c > 0) { float2 t = *(const float2*)(xc - 2); xm2 = t.x; xm1 = t.y; }

    const float4* xv = (const float4*)xc;
    float4* ov = (float4*)(out + (size_t)row * S_LEN + (size_t)c * CHUNK);
    const float inv_sqrt_nb = 0.57735026918962576f;

    float4 buf[4];
    #pragma unroll
    for (int j = 0; j < 4; ++j) buf[j] = xv[j];
    #pragma unroll
    for (int i = 0; i < NV; ++i) {
        float4 q = buf[i & 3];
        if (i + 4 < NV) buf[i & 3] = xv[i + 4];
        float4 o;
        STEP3(q.x, xm2, o.x)
        STEP3(q.y, xm1, o.y)
        STEP3(q.z, q.x, o.z)
        STEP3(q.w, q.y, o.w)
        xm2 = q.z; xm1 = q.w;
        o.x *= inv_sqrt_nb; o.y *= inv_sqrt_nb;
        o.z *= inv_sqrt_nb; o.w *= inv_sqrt_nb;
        ov[i] = o;
    }
}

template<int CHUNK>
static void launch_all(const float* x, const float* lvl, float* out, float* ws,
                       hipStream_t stream)
{
    constexpr int CPR = S_LEN / CHUNK;
    const int total_threads = BATCHES * CPR;
    k1_zerostate<CHUNK><<<total_threads / 256, 256, 0, stream>>>(x, lvl, ws);
    k2_scan<CHUNK><<<BATCHES, 192, 0, stream>>>(lvl, ws);
    k3_apply<CHUNK><<<total_threads / 256, 256, 0, stream>>>(x, lvl, ws, out);
}

extern "C" void kernel_launch(void* const* d_in, const int* in_sizes, int n_in,
                              void* d_out, int out_size, void* d_ws, size_t ws_size,
                              hipStream_t stream) {
    const float* audio = (const float*)d_in[0];
    const float* level = (const float*)d_in[1];
    float* out = (float*)d_out;
    float* ws  = (float*)d_ws;
    (void)in_sizes; (void)n_in; (void)out_size;

    const size_t need64 = (size_t)BATCHES * 6 * (S_LEN / 64) * sizeof(float);  // 12.6 MB
    if (ws_size >= need64)
        launch_all<64>(audio, level, out, ws, stream);
    else
        launch_all<128>(audio, level, out, ws, stream);
}

// Round 3
// 97.797 us; speedup vs baseline: 1.5282x; 1.5282x over previous
//
#include <hip/hip_runtime.h>
#include <math.h>

#ifndef M_PI
#define M_PI 3.14159265358979323846
#endif

#define BATCHES 256
#define S_LEN   131072

__device__ __forceinline__ void compute_coeffs(float level_in, float b0[3], float na1[3], float na2[3]) {
    const float FD[3] = {270.0f, 800.0f, 2300.0f};
    const float FN[3] = {500.0f, 1500.0f, 2500.0f};
    const float FB[3] = {730.0f, 2100.0f, 3000.0f};
    float level = fminf(fmaxf(level_in, 0.0f), 1.0f);
    float t_low  = fminf(fmaxf(level * 2.0f, 0.0f), 1.0f);
    float t_high = fminf(fmaxf((level - 0.5f) * 2.0f, 0.0f), 1.0f);
    bool hi = (level >= 0.5f);
    const float W0 = (float)(2.0 * M_PI / 16000.0);
    #pragma unroll
    for (int k = 0; k < 3; ++k) {
        float f, q;
        if (hi) { f = (1.0f - t_high) * FN[k] + t_high * FB[k];
                  q = (1.0f - t_high) * 8.0f  + t_high * 12.0f; }
        else    { f = (1.0f - t_low) * FD[k] + t_low * FN[k];
                  q = (1.0f - t_low) * 5.0f  + t_low * 8.0f; }
        float omega = W0 * f;
        float sn = sinf(omega), cs = cosf(omega);
        float alpha = sn / (2.0f * fmaxf(q, 0.5f));
        float a0 = 1.0f + alpha;
        b0[k]  = alpha / a0;             // b2 == -b0 exactly
        na1[k] = (2.0f * cs) / a0;       // -a1
        na2[k] = -((1.0f - alpha) / a0); // -a2
    }
}

// One biquad step, 3 bands. Critical chain per band: 1 FMA.
#define STEP3(XT, XTM2, SUMV)                                                    \
    {                                                                            \
        float d = (XT) - (XTM2);                                                 \
        float e0 = fmaf(b0[0], d, na2[0] * y2[0]);                               \
        float e1 = fmaf(b0[1], d, na2[1] * y2[1]);                               \
        float e2 = fmaf(b0[2], d, na2[2] * y2[2]);                               \
        float yy0 = fmaf(na1[0], y1[0], e0);                                     \
        float yy1 = fmaf(na1[1], y1[1], e1);                                     \
        float yy2 = fmaf(na1[2], y1[2], e2);                                     \
        y2[0] = y1[0]; y1[0] = yy0;                                              \
        y2[1] = y1[1]; y1[1] = yy1;                                              \
        y2[2] = y1[2]; y1[2] = yy2;                                              \
        SUMV = (yy0 + yy1 + yy2);                                                \
    }

// ---------------- K1: zero-state response per chunk ----------------
template<int CHUNK>
__global__ __launch_bounds__(256)
void k1_zerostate(const float* __restrict__ x, const float* __restrict__ level_arr,
                  float* __restrict__ ws)
{
    constexpr int CPR = S_LEN / CHUNK;
    constexpr int NV  = CHUNK / 4;
    const int g   = blockIdx.x * 256 + threadIdx.x;
    const int row = g / CPR;
    const int c   = g & (CPR - 1);

    float b0[3], na1[3], na2[3];
    compute_coeffs(level_arr[row], b0, na1, na2);

    const float* xc = x + (size_t)row * S_LEN + (size_t)c * CHUNK;
    float xm1 = 0.f, xm2 = 0.f;
    if (c > 0) { float2 t = *(const float2*)(xc - 2); xm2 = t.x; xm1 = t.y; }

    float y1[3] = {0.f, 0.f, 0.f}, y2[3] = {0.f, 0.f, 0.f};
    const float4* xv = (const float4*)xc;
    float4 buf[4];
    #pragma unroll
    for (int j = 0; j < 4; ++j) buf[j] = xv[j];
    float dummy;
    #pragma unroll
    for (int i = 0; i < NV; ++i) {
        float4 q = buf[i & 3];
        if (i + 4 < NV) buf[i & 3] = xv[i + 4];
        STEP3(q.x, xm2, dummy)
        STEP3(q.y, xm1, dummy)
        STEP3(q.z, q.x, dummy)
        STEP3(q.w, q.y, dummy)
        xm2 = q.z; xm1 = q.w;
    }
    (void)dummy;

    float* wrow = ws + (size_t)row * 6 * CPR;
    wrow[0 * CPR + c] = y1[0]; wrow[1 * CPR + c] = y2[0];
    wrow[2 * CPR + c] = y1[1]; wrow[3 * CPR + c] = y2[1];
    wrow[4 * CPR + c] = y1[2]; wrow[5 * CPR + c] = y2[2];
}

// ---------------- K2: per-row affine scan over chunk states ----------------
template<int CHUNK>
__global__ __launch_bounds__(192)
void k2_scan(const float* __restrict__ level_arr, float* __restrict__ ws)
{
    constexpr int CPR  = S_LEN / CHUNK;
    constexpr int FOLD = CPR / 64;
    constexpr int LSTR = CPR + CPR / 32;
    __shared__ float st[6 * LSTR];

    const int row  = blockIdx.x;
    const int wave = threadIdx.x >> 6;
    const int lane = threadIdx.x & 63;

    float b0[3], na1[3], na2[3];
    compute_coeffs(level_arr[row], b0, na1, na2);
    const float A1 = (wave == 0) ? na1[0] : ((wave == 1) ? na1[1] : na1[2]);
    const float A2 = (wave == 0) ? na2[0] : ((wave == 1) ? na2[1] : na2[2]);

    float* wrow = ws + (size_t)row * 6 * CPR;

    #pragma unroll
    for (int e = 2 * wave; e <= 2 * wave + 1; ++e)
        for (int i = lane; i < CPR; i += 64)
            st[e * LSTR + i + (i >> 5)] = wrow[e * CPR + i];
    __syncthreads();

    float hm1 = 1.f, hm2 = 0.f, hm3 = 0.f;
    for (int i = 0; i < CHUNK; ++i) {
        float h = fmaf(A1, hm1, A2 * hm2);
        hm3 = hm2; hm2 = hm1; hm1 = h;
    }
    const float H00 = hm1, H01 = A2 * hm2;
    const float H10 = hm2, H11 = A2 * hm3;

    float* z1p = st + (2 * wave) * LSTR;
    float* z2p = st + (2 * wave + 1) * LSTR;

    float s1 = 0.f, s2 = 0.f;
    #pragma unroll
    for (int j = 0; j < FOLD; ++j) {
        int cc = lane * FOLD + j, ca = cc + (cc >> 5);
        float z1 = z1p[ca], z2 = z2p[ca];
        float n1 = z1 + H00 * s1 + H01 * s2;
        float n2 = z2 + H10 * s1 + H11 * s2;
        s1 = n1; s2 = n2;
    }
    float P00 = H00, P01 = H01, P10 = H10, P11 = H11;
    #pragma unroll
    for (int t = 0; (1 << t) < FOLD; ++t) {
        float Q00 = P00 * P00 + P01 * P10;
        float Q01 = P00 * P01 + P01 * P11;
        float Q10 = P10 * P00 + P11 * P10;
        float Q11 = P10 * P01 + P11 * P11;
        P00 = Q00; P01 = Q01; P10 = Q10; P11 = Q11;
    }
    float A00 = P00, A01 = P01, A10 = P10, A11 = P11, bb1 = s1, bb2 = s2;
    for (int d = 1; d < 64; d <<= 1) {
        float iA00 = __shfl_up(A00, d), iA01 = __shfl_up(A01, d);
        float iA10 = __shfl_up(A10, d), iA11 = __shfl_up(A11, d);
        float ib1  = __shfl_up(bb1, d), ib2  = __shfl_up(bb2, d);
        if (lane >= d) {
            float nb1 = A00 * ib1 + A01 * ib2 + bb1;
            float nb2 = A10 * ib1 + A11 * ib2 + bb2;
            float n00 = A00 * iA00 + A01 * iA10;
            float n01 = A00 * iA01 + A01 * iA11;
            float n10 = A10 * iA00 + A11 * iA10;
            float n11 = A10 * iA01 + A11 * iA11;
            A00 = n00; A01 = n01; A10 = n10; A11 = n11;
            bb1 = nb1; bb2 = nb2;
        }
    }
    float e1 = __shfl_up(bb1, 1), e2 = __shfl_up(bb2, 1);
    if (lane == 0) { e1 = 0.f; e2 = 0.f; }

    s1 = e1; s2 = e2;
    #pragma unroll
    for (int j = 0; j < FOLD; ++j) {
        int cc = lane * FOLD + j, ca = cc + (cc >> 5);
        float z1 = z1p[ca], z2 = z2p[ca];
        z1p[ca] = s1; z2p[ca] = s2;
        float n1 = z1 + H00 * s1 + H01 * s2;
        float n2 = z2 + H10 * s1 + H11 * s2;
        s1 = n1; s2 = n2;
    }
    __syncthreads();

    #pragma unroll
    for (int e = 2 * wave; e <= 2 * wave + 1; ++e)
        for (int i = lane; i < CPR; i += 64)
            wrow[e * CPR + i] = st[e * LSTR + i + (i >> 5)];
}

// ---------------- K3 (CHUNK=64): recurrence + LDS-staged coalesced output ----------------
__global__ __launch_bounds__(256)
void k3_apply_staged(const float* __restrict__ x, const float* __restrict__ level_arr,
                     const float* __restrict__ ws, float* __restrict__ out)
{
    constexpr int CHUNK = 64;
    constexpr int CPR   = S_LEN / CHUNK;      // 2048
    constexpr int TPB   = 256;
    constexpr int BPR   = CPR / TPB;          // 8 blocks per row
    constexpr int NV    = CHUNK / 4;          // 16
    constexpr int LSTR  = CHUNK + 1;          // 65-float padded chunk stride
    __shared__ float ob[TPB * LSTR];          // 65 KB

    const int tid = threadIdx.x;
    const int row = blockIdx.x / BPR;
    const int seg = blockIdx.x % BPR;
    const int c   = seg * TPB + tid;          // chunk id within row

    float b0[3], na1[3], na2[3];
    compute_coeffs(level_arr[row], b0, na1, na2);

    const float* wrow = ws + (size_t)row * 6 * CPR;
    float y1[3], y2[3];
    y1[0] = wrow[0 * CPR + c]; y2[0] = wrow[1 * CPR + c];
    y1[1] = wrow[2 * CPR + c]; y2[1] = wrow[3 * CPR + c];
    y1[2] = wrow[4 * CPR + c]; y2[2] = wrow[5 * CPR + c];

    const float* xc = x + (size_t)row * S_LEN + (size_t)c * CHUNK;
    float xm1 = 0.f, xm2 = 0.f;
    if (c > 0) { float2 t = *(const float2*)(xc - 2); xm2 = t.x; xm1 = t.y; }

    const float4* xv = (const float4*)xc;
    const float inv_sqrt_nb = 0.57735026918962576f;
    float* myob = ob + tid * LSTR;

    float4 buf[4];
    #pragma unroll
    for (int j = 0; j < 4; ++j) buf[j] = xv[j];
    #pragma unroll
    for (int i = 0; i < NV; ++i) {
        float4 q = buf[i & 3];
        if (i + 4 < NV) buf[i & 3] = xv[i + 4];
        float4 o;
        STEP3(q.x, xm2, o.x)
        STEP3(q.y, xm1, o.y)
        STEP3(q.z, q.x, o.z)
        STEP3(q.w, q.y, o.w)
        xm2 = q.z; xm1 = q.w;
        // scalar LDS writes, bank = (tid + 4i+k) % 32 -> 2-way aliasing (free)
        myob[4 * i + 0] = o.x * inv_sqrt_nb;
        myob[4 * i + 1] = o.y * inv_sqrt_nb;
        myob[4 * i + 2] = o.z * inv_sqrt_nb;
        myob[4 * i + 3] = o.w * inv_sqrt_nb;
    }
    __syncthreads();

    // cooperative coalesced store of the whole 64 KB segment
    float4* obase = (float4*)(out + (size_t)row * S_LEN + (size_t)seg * (TPB * CHUNK));
    #pragma unroll
    for (int j = 0; j < NV; ++j) {
        int f = j * TPB + tid;                // float4 index within segment
        int i = f * 4;
        int ch = i >> 6, off = i & 63;        // chunk + offset (float4 never crosses a chunk)
        const float* p = ob + ch * LSTR + off;
        float4 o = { p[0], p[1], p[2], p[3] };
        obase[f] = o;
    }
}

// ---------------- K3 fallback (CHUNK=128, unstaged) ----------------
template<int CHUNK>
__global__ __launch_bounds__(256)
void k3_apply(const float* __restrict__ x, const float* __restrict__ level_arr,
              const float* __restrict__ ws, float* __restrict__ out)
{
    constexpr int CPR = S_LEN / CHUNK;
    constexpr int NV  = CHUNK / 4;
    const int g   = blockIdx.x * 256 + threadIdx.x;
    const int row = g / CPR;
    const int c   = g & (CPR - 1);

    float b0[3], na1[3], na2[3];
    compute_coeffs(level_arr[row], b0, na1, na2);

    const float* wrow = ws + (size_t)row * 6 * CPR;
    float y1[3], y2[3];
    y1[0] = wrow[0 * CPR + c]; y2[0] = wrow[1 * CPR + c];
    y1[1] = wrow[2 * CPR + c]; y2[1] = wrow[3 * CPR + c];
    y1[2] = wrow[4 * CPR + c]; y2[2] = wrow[5 * CPR + c];

    const float* xc = x + (size_t)row * S_LEN + (size_t)c * CHUNK;
    float xm1 = 0.f, xm2 = 0.f;
    if (c > 0) { float2 t = *(const float2*)(xc - 2); xm2 = t.x; xm1 = t.y; }

    const float4* xv = (const float4*)xc;
    float4* ov = (float4*)(out + (size_t)row * S_LEN + (size_t)c * CHUNK);
    const float inv_sqrt_nb = 0.57735026918962576f;

    float4 buf[4];
    #pragma unroll
    for (int j = 0; j < 4; ++j) buf[j] = xv[j];
    #pragma unroll
    for (int i = 0; i < NV; ++i) {
        float4 q = buf[i & 3];
        if (i + 4 < NV) buf[i & 3] = xv[i + 4];
        float4 o;
        STEP3(q.x, xm2, o.x)
        STEP3(q.y, xm1, o.y)
        STEP3(q.z, q.x, o.z)
        STEP3(q.w, q.y, o.w)
        xm2 = q.z; xm1 = q.w;
        o.x *= inv_sqrt_nb; o.y *= inv_sqrt_nb;
        o.z *= inv_sqrt_nb; o.w *= inv_sqrt_nb;
        ov[i] = o;
    }
}

extern "C" void kernel_launch(void* const* d_in, const int* in_sizes, int n_in,
                              void* d_out, int out_size, void* d_ws, size_t ws_size,
                              hipStream_t stream) {
    const float* audio = (const float*)d_in[0];
    const float* level = (const float*)d_in[1];
    float* out = (float*)d_out;
    float* ws  = (float*)d_ws;
    (void)in_sizes; (void)n_in; (void)out_size;

    const size_t need64 = (size_t)BATCHES * 6 * (S_LEN / 64) * sizeof(float);  // 12.6 MB
    if (ws_size >= need64) {
        constexpr int CHUNK = 64;
        constexpr int CPR = S_LEN / CHUNK;
        const int total_threads = BATCHES * CPR;
        k1_zerostate<CHUNK><<<total_threads / 256, 256, 0, stream>>>(audio, level, ws);
        k2_scan<CHUNK><<<BATCHES, 192, 0, stream>>>(level, ws);
        k3_apply_staged<<<total_threads / 256, 256, 0, stream>>>(audio, level, ws, out);
    } else {
        constexpr int CHUNK = 128;
        constexpr int CPR = S_LEN / CHUNK;
        const int total_threads = BATCHES * CPR;
        k1_zerostate<CHUNK><<<total_threads / 256, 256, 0, stream>>>(audio, level, ws);
        k2_scan<CHUNK><<<BATCHES, 192, 0, stream>>>(level, ws);
        k3_apply<CHUNK><<<total_threads / 256, 256, 0, stream>>>(audio, level, ws, out);
    }
}